// Round 6
// baseline (889.292 us; speedup 1.0000x reference)
//
#include <hip/hip_runtime.h>
#include <cstdint>

// RandomMaskSubgraphs — R6: single fused kernel, hand-rolled grid barrier.
//  - 512 blocks x 256 threads (co-residency GUARANTEED by arithmetic:
//    __launch_bounds__(256,2) => VGPR<=256 => >=2 blocks/CU by waves;
//    LDS 50KB => 3/CU; so capacity >= 512 = grid). No cooperative API
//    (R5's hipLaunchCooperativeKernel silently refused to launch).
//  - Sense-reversal barrier: (count,gen) device-scope atomics + threadfence
//    release/acquire — same fence pattern R4's ticket tails validated.
//    bar zeroed via hipMemsetAsync (graph-capturable) each call.
//  - Each thread owns 7 int4-chunks of edges in REGISTERS (edges read from
//    HBM exactly once) + 28 mask bits in one uint32.
//  - Threefry scores recomputed on the fly (no score arrays).
//  - Degree: per-block LDS nibble histogram (512 planes -> d_out scratch,
//    25.6 MB), packed-byte reduce, rsqrt.
//  - Exact k-smallest selection (2048-bin hist + per-block replicated scan +
//    boundary-bin stable rank) — numerically identical to R1/R2/R4 (absmax 0).

#define NNODES 100000
#define TWON   200000
#define NBINS  2048
#define SBW    3136
#define NLIST  2048
#define NBLK   512
#define NTHR   256
#define TOT    (NBLK * NTHR)   // 131072
#define NCHK   7               // ceil(800000 / 131072)

__host__ __device__ inline uint32_t rotl32(uint32_t v, int d) {
    return (v << d) | (v >> (32 - d));
}

__host__ __device__ inline void tf2x32(uint32_t k0, uint32_t k1,
                                       uint32_t x0, uint32_t x1,
                                       uint32_t& y0, uint32_t& y1) {
    uint32_t k2 = k0 ^ k1 ^ 0x1BD11BDAu;
    x0 += k0; x1 += k1;
    #pragma unroll
    for (int g = 0; g < 5; ++g) {
        const int ra[4] = {13, 15, 26, 6};
        const int rb[4] = {17, 29, 16, 24};
        if ((g & 1) == 0) {
            #pragma unroll
            for (int j = 0; j < 4; ++j) { x0 += x1; x1 = rotl32(x1, ra[j]); x1 ^= x0; }
        } else {
            #pragma unroll
            for (int j = 0; j < 4; ++j) { x0 += x1; x1 = rotl32(x1, rb[j]); x1 ^= x0; }
        }
        uint32_t ks[3] = {k0, k1, k2};
        x0 += ks[(g + 1) % 3];
        x1 += ks[(g + 2) % 3] + (uint32_t)(g + 1);
    }
    y0 = x0; y1 = x1;
}

__device__ inline float uscore(uint32_t ka, uint32_t kb, uint32_t s) {
    uint32_t y0, y1;
    tf2x32(ka, kb, 0u, s, y0, y1);
    uint32_t fb = 0x3f800000u | ((y0 ^ y1) >> 9);
    return __uint_as_float(fb) - 1.0f;
}

__device__ inline uint32_t sbtest(const uint32_t* sb, int a, int b) {
    return ((sb[a >> 5] >> (a & 31)) | (sb[b >> 5] >> (b & 31))) & 1u;
}

__device__ inline int aload(const int* p) {
    return __hip_atomic_load(p, __ATOMIC_RELAXED, __HIP_MEMORY_SCOPE_AGENT);
}

__device__ inline int binof(float u) {
    int b = (int)(u * 2048.0f);
    return (b > NBINS - 1) ? NBINS - 1 : b;
}

// Sense-reversal grid barrier. All blocks co-resident (see launch math).
__device__ inline void gridbar(int* bar) {
    __syncthreads();
    if (threadIdx.x == 0) {
        __threadfence();    // release: make this block's writes device-visible
        int g = __hip_atomic_load(&bar[1], __ATOMIC_ACQUIRE, __HIP_MEMORY_SCOPE_AGENT);
        int a = __hip_atomic_fetch_add(&bar[0], 1, __ATOMIC_ACQ_REL, __HIP_MEMORY_SCOPE_AGENT);
        if (a == NBLK - 1) {
            __hip_atomic_store(&bar[0], 0, __ATOMIC_RELAXED, __HIP_MEMORY_SCOPE_AGENT);
            __hip_atomic_fetch_add(&bar[1], 1, __ATOMIC_ACQ_REL, __HIP_MEMORY_SCOPE_AGENT);
        } else {
            while (__hip_atomic_load(&bar[1], __ATOMIC_ACQUIRE, __HIP_MEMORY_SCOPE_AGENT) == g)
                __builtin_amdgcn_s_sleep(4);
        }
        __threadfence();    // acquire: invalidate caches before plain reads
    }
    __syncthreads();
}

struct SelShared { int hist[NBINS]; int part[NTHR]; };
struct RankShared { int list[NLIST]; float score[NLIST]; };

__global__ __launch_bounds__(NTHR, 2) void k_fused(
        const int4* __restrict__ r4, const int4* __restrict__ c4,
        const int* __restrict__ seeds, int nSeeds,
        uint32_t* __restrict__ sbA, uint32_t* __restrict__ sbB,
        unsigned char* __restrict__ cand,
        int* __restrict__ hist, int* __restrict__ scal,
        int* __restrict__ glist, float* __restrict__ dinv,
        uint32_t* __restrict__ planes,
        float4* __restrict__ enc4, float4* __restrict__ msk4,
        int* __restrict__ bar, int E4,
        uint32_t ka0, uint32_t kb0, uint32_t ka1, uint32_t kb1) {
    __shared__ union {
        uint32_t nib[12500];
        uint32_t seedb[SBW];
        SelShared sel;
        RankShared rank;
    } sm;
    __shared__ int sTR[2];

    const int t = threadIdx.x;
    const int b = blockIdx.x;
    const int gid = b * NTHR + t;

    // ---- P0: load edge chunks into registers; zero cand/hist/scal; seeds ----
    int4 rr[NCHK], cc[NCHK];
    bool vld[NCHK];
    #pragma unroll
    for (int k = 0; k < NCHK; ++k) {
        int idx = gid + k * TOT;
        vld[k] = (idx < E4);
        rr[k] = vld[k] ? r4[idx] : make_int4(0, 0, 0, 0);
        cc[k] = vld[k] ? c4[idx] : make_int4(0, 0, 0, 0);
    }
    if (gid < TWON / 4) ((uint32_t*)cand)[gid] = 0;
    if (gid < NBINS) hist[gid] = 0;
    if (gid < 8) scal[gid] = 0;
    if (b == 0) {
        for (int i = t; i < SBW; i += NTHR) sm.seedb[i] = 0;
        __syncthreads();
        for (int i = t; i < nSeeds; i += NTHR) {
            int s = seeds[i];
            if (s < NNODES) atomicOr(&sm.seedb[s >> 5], 1u << (s & 31));
        }
        __syncthreads();
        for (int i = t; i < SBW; i += NTHR) sbA[i] = sm.seedb[i];
    }
    gridbar(bar);

    uint32_t mkb = 0;               // 28 per-edge masked bits (7 chunks x 4)
    uint32_t* sbIn = sbA;
    uint32_t* sbOut = sbB;

    #define MARKC(RRW, CCW, BIT, WC) do { \
        if (!((mkb >> (BIT)) & 1u) && sbtest(sbIn, (RRW), (CCW))) { \
            mkb |= 1u << (BIT); \
            if (WC) cand[(RRW) + (CCW)] = 1; } } while (0)
    #define MARKALL(WC) do { \
        _Pragma("unroll") \
        for (int k = 0; k < NCHK; ++k) { \
            if (!vld[k]) continue; \
            MARKC(rr[k].x, cc[k].x, 4 * k + 0, WC); \
            MARKC(rr[k].y, cc[k].y, 4 * k + 1, WC); \
            MARKC(rr[k].z, cc[k].z, 4 * k + 2, WC); \
            MARKC(rr[k].w, cc[k].w, 4 * k + 3, WC); } } while (0)

    for (int iter = 0; iter < 2; ++iter) {
        const uint32_t ka = iter ? ka1 : ka0;
        const uint32_t kb = iter ? kb1 : kb0;

        // ---- mark: set bits, record candidates ----
        MARKALL(true);
        gridbar(bar);

        // ---- histogram of candidate score bins (2 strides/thread) ----
        int cbin0 = -1, cbin1 = -1;
        if (cand[gid]) {
            cbin0 = binof(uscore(ka, kb, (uint32_t)gid));
            atomicAdd(&hist[cbin0], 1);
        }
        {
            int s1 = gid + TOT;
            if (s1 < TWON && cand[s1]) {
                cbin1 = binof(uscore(ka, kb, (uint32_t)s1));
                atomicAdd(&hist[cbin1], 1);
            }
        }
        gridbar(bar);

        // ---- per-block replicated scan -> T (threshold bin), R (in-bin k) ----
        for (int i = t; i < NBINS; i += NTHR) sm.sel.hist[i] = aload(&hist[i]);
        if (t < 2) sTR[t] = (t == 0) ? -1 : 0;
        __syncthreads();
        int h[8], ssum = 0;
        #pragma unroll
        for (int j = 0; j < 8; ++j) { h[j] = sm.sel.hist[8 * t + j]; ssum += h[j]; }
        sm.sel.part[t] = ssum;
        __syncthreads();
        for (int d = 1; d < NTHR; d <<= 1) {
            int w = (t >= d) ? sm.sel.part[t - d] : 0;
            __syncthreads();
            sm.sel.part[t] += w;
            __syncthreads();
        }
        int total = sm.sel.part[NTHR - 1];
        int kk = total >> (iter + 1);        // floor(count * 0.5^(i+1)), exact
        int base = (t > 0) ? sm.sel.part[t - 1] : 0;
        if (total > 0) {
            int cum = base;
            #pragma unroll
            for (int j = 0; j < 8; ++j) {
                if (h[j] > 0 && cum <= kk && kk < cum + h[j]) {
                    sTR[0] = 8 * t + j; sTR[1] = kk - cum;
                }
                cum += h[j];
            }
        }
        __syncthreads();
        const int T = sTR[0];

        // ---- select: ballot bits (stride 0 covers all node-id bits),
        //      boundary-bin members -> glist, zero cand ----
        {
            bool sel0 = (cbin0 >= 0) && (cbin0 < T);
            unsigned long long bb = __ballot(sel0);
            int lane = t & 63;
            int wb = gid - lane;
            if (lane == 0 && wb < 100032) {
                sbOut[(wb >> 5)]     = (uint32_t)bb;
                sbOut[(wb >> 5) + 1] = (uint32_t)(bb >> 32);
            }
            if (cbin0 == T) {
                int idx = atomicAdd(&scal[iter], 1);
                if (idx < NLIST) glist[idx] = gid;
            }
            if (cbin1 == T) {
                int idx = atomicAdd(&scal[iter], 1);
                if (idx < NLIST) glist[idx] = gid + TOT;
            }
            cand[gid] = 0;
            if (gid + TOT < TWON) cand[gid + TOT] = 0;
        }
        gridbar(bar);

        // ---- rank (block 0): exact stable (score,index) rank in boundary bin;
        //      block 1: zero hist for next iteration ----
        if (b == 0) {
            const int R = aload(&scal[iter + 4]) ? 0 : 0;  // (placeholder keep regs tight)
            int Rr = sTR[1];
            int n = aload(&scal[iter]); if (n > NLIST) n = NLIST;
            for (int i = t; i < n; i += NTHR) {
                int si = aload(&glist[i]);
                sm.rank.list[i] = si;
                sm.rank.score[i] = uscore(ka, kb, (uint32_t)si);
            }
            __syncthreads();
            for (int x = t; x < n; x += NTHR) {
                int st = sm.rank.list[x];
                float ut = sm.rank.score[x];
                int rk = 0;
                for (int j = 0; j < n; ++j) {
                    float uj = sm.rank.score[j];
                    int sj = sm.rank.list[j];
                    rk += (uj < ut || (uj == ut && sj < st)) ? 1 : 0;
                }
                if (rk < Rr && st < NNODES) atomicOr(&sbOut[st >> 5], 1u << (st & 31));
            }
            (void)R;
        } else if (b == 1) {
            for (int i = t; i < NBINS; i += NTHR) hist[i] = 0;
        }
        gridbar(bar);

        uint32_t* tmp = sbIn; sbIn = sbOut; sbOut = tmp;
    }

    // ---- final mark + LDS nibble degree -> plane ----
    MARKALL(false);
    for (int i = t; i < 12500; i += NTHR) sm.nib[i] = 0;
    __syncthreads();
    #define DADD(RRW, BIT) do { \
        if (vldk && !((mkb >> (BIT)) & 1u)) \
            atomicAdd(&sm.nib[(RRW) >> 3], 1u << (((RRW) & 7) * 4)); } while (0)
    #pragma unroll
    for (int k = 0; k < NCHK; ++k) {
        bool vldk = vld[k];
        DADD(rr[k].x, 4 * k + 0);
        DADD(rr[k].y, 4 * k + 1);
        DADD(rr[k].z, 4 * k + 2);
        DADD(rr[k].w, 4 * k + 3);
    }
    __syncthreads();
    {
        uint32_t* mine = planes + b * 12500;
        for (int i = t; i < 12500; i += NTHR) mine[i] = sm.nib[i];
    }
    gridbar(bar);

    // ---- reduce: 8 threads/column over 512 planes, packed-byte sums ----
    if (gid < NNODES) {
        int col = gid >> 3, sub = gid & 7;
        uint32_t lo = 0, hi = 0;
        int p0 = sub * (NBLK / 8);
        #pragma unroll 8
        for (int p = p0; p < p0 + NBLK / 8; ++p) {
            uint32_t v = planes[p * 12500 + col];
            lo += v & 0x0F0F0F0Fu;
            hi += (v >> 4) & 0x0F0F0F0Fu;
        }
        lo += __shfl_xor(lo, 1);  hi += __shfl_xor(hi, 1);
        lo += __shfl_xor(lo, 2);  hi += __shfl_xor(hi, 2);
        lo += __shfl_xor(lo, 4);  hi += __shfl_xor(hi, 4);
        if (sub == 0) {
            int nbase = col * 8;
            #pragma unroll
            for (int q = 0; q < 4; ++q) {
                float d0 = (float)((lo >> (8 * q)) & 0xFFu);
                float d1 = (float)((hi >> (8 * q)) & 0xFFu);
                dinv[nbase + 2 * q]     = rsqrtf(d0 + 1e-12f);
                dinv[nbase + 2 * q + 1] = rsqrtf(d1 + 1e-12f);
            }
        }
    }
    gridbar(bar);

    // ---- out ----
    #pragma unroll
    for (int k = 0; k < NCHK; ++k) {
        if (!vld[k]) continue;
        uint32_t mb = mkb >> (4 * k);
        float4 ev, mv;
        ev.x = (mb & 1u) ? 0.0f : dinv[rr[k].x] * dinv[cc[k].x];  mv.x = (mb & 1u) ? 1.0f : 0.0f;
        ev.y = (mb & 2u) ? 0.0f : dinv[rr[k].y] * dinv[cc[k].y];  mv.y = (mb & 2u) ? 1.0f : 0.0f;
        ev.z = (mb & 4u) ? 0.0f : dinv[rr[k].z] * dinv[cc[k].z];  mv.z = (mb & 4u) ? 1.0f : 0.0f;
        ev.w = (mb & 8u) ? 0.0f : dinv[rr[k].w] * dinv[cc[k].w];  mv.w = (mb & 8u) ? 1.0f : 0.0f;
        int idx = gid + k * TOT;
        enc4[idx] = ev;
        msk4[idx] = mv;
    }
}

extern "C" void kernel_launch(void* const* d_in, const int* in_sizes, int n_in,
                              void* d_out, int out_size, void* d_ws, size_t ws_size,
                              hipStream_t stream) {
    const int4* rows4 = (const int4*)d_in[0];
    const int4* cols4 = (const int4*)d_in[1];
    const int* seeds  = (const int*)d_in[3];
    int E      = in_sizes[0];    // 3,200,000
    int nSeeds = in_sizes[3];
    int E4     = E / 4;          // 800,000

    float* enc = (float*)d_out;
    float4* enc4p = (float4*)d_out;
    float4* msk4p = (float4*)(enc + E);
    uint32_t* planes = (uint32_t*)d_out;   // 512*12500*4 B = 25.6 MB = |d_out|

    char* p = (char*)d_ws;
    uint32_t* sbA = (uint32_t*)p; p += SBW * 4;
    uint32_t* sbB = (uint32_t*)p; p += SBW * 4;
    float* dinv   = (float*)p;    p += NNODES * 4;
    int* hist     = (int*)p;      p += NBINS * 4;
    int* scal     = (int*)p;      p += 8 * 4;
    int* glist    = (int*)p;      p += NLIST * 4;
    int* bar      = (int*)p;      p += 16 * 4;   // count, gen (own cacheline)
    unsigned char* cand = (unsigned char*)p; p += TWON;
    // total ws use: ~0.65 MB

    uint32_t ka0, kb0, ka1, kb1;
    tf2x32(0u, 42u, 0u, 0u, ka0, kb0);
    tf2x32(0u, 42u, 0u, 1u, ka1, kb1);

    hipMemsetAsync(bar, 0, 64, stream);   // graph-capturable memset node
    k_fused<<<dim3(NBLK), dim3(NTHR), 0, stream>>>(
        rows4, cols4, seeds, nSeeds, sbA, sbB, cand, hist, scal, glist,
        dinv, planes, enc4p, msk4p, bar, E4, ka0, kb0, ka1, kb1);
}

// Round 7
// 269.187 us; speedup vs baseline: 3.3036x; 3.3036x over previous
//
#include <hip/hip_runtime.h>
#include <cstdint>

// RandomMaskSubgraphs — R7: fused kernel, FIXED grid barrier.
//  R6 post-mortem: 917us with VALUBusy 1% — the barrier's ACQ_REL arrivals
//  (full L2 wb+inv per block per barrier) and ACQUIRE-load spin (buffer_inv
//  per poll!) were a cache-maintenance storm on non-coherent XCD L2s.
//  Fixes: RELAXED spin loads (sc-bits bypass caches, no inv), RELEASE-only
//  arrivals, ONE acquire fence at exit, 8 padded sub-counters -> root -> gen.
//  Also: per-block LDS seed mask kills the P0 barrier; memset node zeroes
//  bar/hist/scal/cand (218 KB). 10 barriers total.
//  Phase logic verbatim from R6 (absmax 0.0 verified).

#define NNODES 100000
#define TWON   200000
#define NBINS  2048
#define SBW    3136
#define NLIST  2048
#define NBLK   512
#define NTHR   256
#define TOT    (NBLK * NTHR)   // 131072
#define NCHK   7               // ceil(800000 / 131072)

#define ROOT_IDX 256           // bar[] int indices (128B-padded lines)
#define GEN_IDX  288

__host__ __device__ inline uint32_t rotl32(uint32_t v, int d) {
    return (v << d) | (v >> (32 - d));
}

__host__ __device__ inline void tf2x32(uint32_t k0, uint32_t k1,
                                       uint32_t x0, uint32_t x1,
                                       uint32_t& y0, uint32_t& y1) {
    uint32_t k2 = k0 ^ k1 ^ 0x1BD11BDAu;
    x0 += k0; x1 += k1;
    #pragma unroll
    for (int g = 0; g < 5; ++g) {
        const int ra[4] = {13, 15, 26, 6};
        const int rb[4] = {17, 29, 16, 24};
        if ((g & 1) == 0) {
            #pragma unroll
            for (int j = 0; j < 4; ++j) { x0 += x1; x1 = rotl32(x1, ra[j]); x1 ^= x0; }
        } else {
            #pragma unroll
            for (int j = 0; j < 4; ++j) { x0 += x1; x1 = rotl32(x1, rb[j]); x1 ^= x0; }
        }
        uint32_t ks[3] = {k0, k1, k2};
        x0 += ks[(g + 1) % 3];
        x1 += ks[(g + 2) % 3] + (uint32_t)(g + 1);
    }
    y0 = x0; y1 = x1;
}

__device__ inline float uscore(uint32_t ka, uint32_t kb, uint32_t s) {
    uint32_t y0, y1;
    tf2x32(ka, kb, 0u, s, y0, y1);
    uint32_t fb = 0x3f800000u | ((y0 ^ y1) >> 9);
    return __uint_as_float(fb) - 1.0f;
}

__device__ inline uint32_t sbtest(const uint32_t* sb, int a, int b) {
    return ((sb[a >> 5] >> (a & 31)) | (sb[b >> 5] >> (b & 31))) & 1u;
}

__device__ inline int binof(float u) {
    int b = (int)(u * 2048.0f);
    return (b > NBINS - 1) ? NBINS - 1 : b;
}

// Grid barrier: RELEASE arrivals (one dirty-L2 wb each, no inv), RELAXED
// spin (cache-bypassing loads, zero cache maintenance), single ACQUIRE
// fence at exit. Hierarchical: 8 sub-counters (64 blocks each) -> root.
__device__ inline void gridbar(int* bar) {
    __syncthreads();
    if (threadIdx.x == 0) {
        int g = __hip_atomic_load(&bar[GEN_IDX], __ATOMIC_RELAXED, __HIP_MEMORY_SCOPE_AGENT);
        int sub = (blockIdx.x & 7) * 32;
        int a = __hip_atomic_fetch_add(&bar[sub], 1, __ATOMIC_RELEASE, __HIP_MEMORY_SCOPE_AGENT);
        bool released = false;
        if (a == NBLK / 8 - 1) {
            __hip_atomic_store(&bar[sub], 0, __ATOMIC_RELAXED, __HIP_MEMORY_SCOPE_AGENT);
            int r = __hip_atomic_fetch_add(&bar[ROOT_IDX], 1, __ATOMIC_RELEASE, __HIP_MEMORY_SCOPE_AGENT);
            if (r == 7) {
                __hip_atomic_store(&bar[ROOT_IDX], 0, __ATOMIC_RELAXED, __HIP_MEMORY_SCOPE_AGENT);
                __hip_atomic_fetch_add(&bar[GEN_IDX], 1, __ATOMIC_RELEASE, __HIP_MEMORY_SCOPE_AGENT);
                released = true;
            }
        }
        if (!released) {
            while (__hip_atomic_load(&bar[GEN_IDX], __ATOMIC_RELAXED, __HIP_MEMORY_SCOPE_AGENT) == g)
                __builtin_amdgcn_s_sleep(8);
        }
        __builtin_amdgcn_fence(__ATOMIC_ACQUIRE, "agent");
    }
    __syncthreads();
}

struct SelShared { int hist[NBINS]; int part[NTHR]; };
struct RankShared { int list[NLIST]; float score[NLIST]; };

__global__ __launch_bounds__(NTHR, 2) void k_fused(
        const int4* __restrict__ r4, const int4* __restrict__ c4,
        const int* __restrict__ seeds, int nSeeds,
        uint32_t* __restrict__ sb1, uint32_t* __restrict__ sb2,
        unsigned char* __restrict__ cand,
        int* __restrict__ hist0, int* __restrict__ hist1,
        int* __restrict__ scal, int* __restrict__ glist,
        float* __restrict__ dinv, uint32_t* __restrict__ planes,
        float4* __restrict__ enc4, float4* __restrict__ msk4,
        int* __restrict__ bar, int E4,
        uint32_t ka0, uint32_t kb0, uint32_t ka1, uint32_t kb1) {
    __shared__ union {
        uint32_t nib[12500];
        uint32_t seedb[SBW];
        SelShared sel;
        RankShared rank;
    } sm;
    __shared__ int sTR[2];

    const int t = threadIdx.x;
    const int b = blockIdx.x;
    const int gid = b * NTHR + t;

    // ---- P0: edges -> registers; per-block LDS seed bitmask ----
    int4 rr[NCHK], cc[NCHK];
    bool vld[NCHK];
    #pragma unroll
    for (int k = 0; k < NCHK; ++k) {
        int idx = gid + k * TOT;
        vld[k] = (idx < E4);
        rr[k] = vld[k] ? r4[idx] : make_int4(0, 0, 0, 0);
        cc[k] = vld[k] ? c4[idx] : make_int4(0, 0, 0, 0);
    }
    for (int i = t; i < SBW; i += NTHR) sm.seedb[i] = 0;
    __syncthreads();
    for (int i = t; i < nSeeds; i += NTHR) {
        int s = seeds[i];
        if (s < NNODES) atomicOr(&sm.seedb[s >> 5], 1u << (s & 31));
    }
    __syncthreads();

    uint32_t mkb = 0;   // 28 per-edge masked bits

    #define MARKC(SBP, RRW, CCW, BIT, WC) do { \
        if (!((mkb >> (BIT)) & 1u) && sbtest((SBP), (RRW), (CCW))) { \
            mkb |= 1u << (BIT); \
            if (WC) cand[(RRW) + (CCW)] = 1; } } while (0)
    #define MARKALL(SBP, WC) do { \
        _Pragma("unroll") \
        for (int k = 0; k < NCHK; ++k) { \
            if (!vld[k]) continue; \
            MARKC(SBP, rr[k].x, cc[k].x, 4 * k + 0, WC); \
            MARKC(SBP, rr[k].y, cc[k].y, 4 * k + 1, WC); \
            MARKC(SBP, rr[k].z, cc[k].z, 4 * k + 2, WC); \
            MARKC(SBP, rr[k].w, cc[k].w, 4 * k + 3, WC); } } while (0)

    // ---- mark0 (LDS seed mask; cand/hist/scal pre-zeroed by memset) ----
    MARKALL((const uint32_t*)sm.seedb, true);
    gridbar(bar);                                           // B1

    for (int iter = 0; iter < 2; ++iter) {
        const uint32_t ka = iter ? ka1 : ka0;
        const uint32_t kb = iter ? kb1 : kb0;
        int* hist = iter ? hist1 : hist0;
        uint32_t* sbOut = iter ? sb2 : sb1;

        // ---- histogram of candidate score bins ----
        int cbin0 = -1, cbin1 = -1;
        if (cand[gid]) {
            cbin0 = binof(uscore(ka, kb, (uint32_t)gid));
            atomicAdd(&hist[cbin0], 1);
        }
        {
            int s1 = gid + TOT;
            if (s1 < TWON && cand[s1]) {
                cbin1 = binof(uscore(ka, kb, (uint32_t)s1));
                atomicAdd(&hist[cbin1], 1);
            }
        }
        gridbar(bar);                                       // B2 / B6

        // ---- per-block replicated scan -> T, R ----
        for (int i = t; i < NBINS; i += NTHR) sm.sel.hist[i] = hist[i];
        if (t < 2) sTR[t] = (t == 0) ? -1 : 0;
        __syncthreads();
        int h[8], ssum = 0;
        #pragma unroll
        for (int j = 0; j < 8; ++j) { h[j] = sm.sel.hist[8 * t + j]; ssum += h[j]; }
        sm.sel.part[t] = ssum;
        __syncthreads();
        for (int d = 1; d < NTHR; d <<= 1) {
            int w = (t >= d) ? sm.sel.part[t - d] : 0;
            __syncthreads();
            sm.sel.part[t] += w;
            __syncthreads();
        }
        int total = sm.sel.part[NTHR - 1];
        int kk = total >> (iter + 1);        // floor(count * 0.5^(i+1)), exact
        int base = (t > 0) ? sm.sel.part[t - 1] : 0;
        if (total > 0) {
            int cum = base;
            #pragma unroll
            for (int j = 0; j < 8; ++j) {
                if (h[j] > 0 && cum <= kk && kk < cum + h[j]) {
                    sTR[0] = 8 * t + j; sTR[1] = kk - cum;
                }
                cum += h[j];
            }
        }
        __syncthreads();
        const int T = sTR[0];

        // ---- select: ballot bits, boundary -> glist, zero own cand ----
        {
            bool sel0 = (cbin0 >= 0) && (cbin0 < T);
            unsigned long long bb = __ballot(sel0);
            int lane = t & 63;
            int wb = gid - lane;
            if (lane == 0 && wb < 100032) {
                sbOut[(wb >> 5)]     = (uint32_t)bb;
                sbOut[(wb >> 5) + 1] = (uint32_t)(bb >> 32);
            }
            if (cbin0 == T) {
                int idx = atomicAdd(&scal[iter], 1);
                if (idx < NLIST) glist[idx] = gid;
            }
            if (cbin1 == T) {
                int idx = atomicAdd(&scal[iter], 1);
                if (idx < NLIST) glist[idx] = gid + TOT;
            }
            cand[gid] = 0;
            if (gid + TOT < TWON) cand[gid + TOT] = 0;
        }
        gridbar(bar);                                       // B3 / B7

        // ---- rank (block 0): exact stable (score,index) in boundary bin ----
        if (b == 0) {
            int Rr = sTR[1];
            int n = scal[iter]; if (n > NLIST) n = NLIST;
            for (int i = t; i < n; i += NTHR) {
                int si = glist[i];
                sm.rank.list[i] = si;
                sm.rank.score[i] = uscore(ka, kb, (uint32_t)si);
            }
            __syncthreads();
            for (int x = t; x < n; x += NTHR) {
                int st = sm.rank.list[x];
                float ut = sm.rank.score[x];
                int rk = 0;
                for (int j = 0; j < n; ++j) {
                    float uj = sm.rank.score[j];
                    int sj = sm.rank.list[j];
                    rk += (uj < ut || (uj == ut && sj < st)) ? 1 : 0;
                }
                if (rk < Rr && st < NNODES) atomicOr(&sbOut[st >> 5], 1u << (st & 31));
            }
        }
        gridbar(bar);                                       // B4 / B8

        // ---- mark with new seed set (iter0 -> prepares cand for iter1;
        //      iter1's mark is fused with degree below) ----
        if (iter == 0) {
            MARKALL(sb1, true);
            gridbar(bar);                                   // B5
        }
    }

    // ---- final mark + LDS nibble degree -> plane ----
    MARKALL(sb2, false);
    for (int i = t; i < 12500; i += NTHR) sm.nib[i] = 0;
    __syncthreads();
    #define DADD(RRW, BIT) do { \
        if (vldk && !((mkb >> (BIT)) & 1u)) \
            atomicAdd(&sm.nib[(RRW) >> 3], 1u << (((RRW) & 7) * 4)); } while (0)
    #pragma unroll
    for (int k = 0; k < NCHK; ++k) {
        bool vldk = vld[k];
        DADD(rr[k].x, 4 * k + 0);
        DADD(rr[k].y, 4 * k + 1);
        DADD(rr[k].z, 4 * k + 2);
        DADD(rr[k].w, 4 * k + 3);
    }
    __syncthreads();
    {
        uint32_t* mine = planes + b * 12500;
        for (int i = t; i < 12500; i += NTHR) mine[i] = sm.nib[i];
    }
    gridbar(bar);                                           // B9

    // ---- reduce: 8 threads/column over 512 planes ----
    if (gid < NNODES) {
        int col = gid >> 3, sub = gid & 7;
        uint32_t lo = 0, hi = 0;
        int p0 = sub * (NBLK / 8);
        #pragma unroll 8
        for (int p = p0; p < p0 + NBLK / 8; ++p) {
            uint32_t v = planes[p * 12500 + col];
            lo += v & 0x0F0F0F0Fu;
            hi += (v >> 4) & 0x0F0F0F0Fu;
        }
        lo += __shfl_xor(lo, 1);  hi += __shfl_xor(hi, 1);
        lo += __shfl_xor(lo, 2);  hi += __shfl_xor(hi, 2);
        lo += __shfl_xor(lo, 4);  hi += __shfl_xor(hi, 4);
        if (sub == 0) {
            int nbase = col * 8;
            #pragma unroll
            for (int q = 0; q < 4; ++q) {
                float d0 = (float)((lo >> (8 * q)) & 0xFFu);
                float d1 = (float)((hi >> (8 * q)) & 0xFFu);
                dinv[nbase + 2 * q]     = rsqrtf(d0 + 1e-12f);
                dinv[nbase + 2 * q + 1] = rsqrtf(d1 + 1e-12f);
            }
        }
    }
    gridbar(bar);                                           // B10

    // ---- out ----
    #pragma unroll
    for (int k = 0; k < NCHK; ++k) {
        if (!vld[k]) continue;
        uint32_t mb = mkb >> (4 * k);
        float4 ev, mv;
        ev.x = (mb & 1u) ? 0.0f : dinv[rr[k].x] * dinv[cc[k].x];  mv.x = (mb & 1u) ? 1.0f : 0.0f;
        ev.y = (mb & 2u) ? 0.0f : dinv[rr[k].y] * dinv[cc[k].y];  mv.y = (mb & 2u) ? 1.0f : 0.0f;
        ev.z = (mb & 4u) ? 0.0f : dinv[rr[k].z] * dinv[cc[k].z];  mv.z = (mb & 4u) ? 1.0f : 0.0f;
        ev.w = (mb & 8u) ? 0.0f : dinv[rr[k].w] * dinv[cc[k].w];  mv.w = (mb & 8u) ? 1.0f : 0.0f;
        int idx = gid + k * TOT;
        enc4[idx] = ev;
        msk4[idx] = mv;
    }
}

extern "C" void kernel_launch(void* const* d_in, const int* in_sizes, int n_in,
                              void* d_out, int out_size, void* d_ws, size_t ws_size,
                              hipStream_t stream) {
    const int4* rows4 = (const int4*)d_in[0];
    const int4* cols4 = (const int4*)d_in[1];
    const int* seeds  = (const int*)d_in[3];
    int E      = in_sizes[0];    // 3,200,000
    int nSeeds = in_sizes[3];
    int E4     = E / 4;          // 800,000

    float* enc = (float*)d_out;
    float4* enc4p = (float4*)d_out;
    float4* msk4p = (float4*)(enc + E);
    uint32_t* planes = (uint32_t*)d_out;   // 512*12500*4 B = 25.6 MB

    // ws layout: [memset region: bar | hist0 | hist1 | scal | cand] [rest]
    char* p = (char*)d_ws;
    int* bar      = (int*)p;      p += 320 * 4;       // padded counter lines
    int* hist0    = (int*)p;      p += NBINS * 4;
    int* hist1    = (int*)p;      p += NBINS * 4;
    int* scal     = (int*)p;      p += 8 * 4;
    unsigned char* cand = (unsigned char*)p; p += TWON;
    size_t zlen = (size_t)(p - (char*)d_ws);          // 217,696 B
    uint32_t* sb1 = (uint32_t*)p; p += SBW * 4;
    uint32_t* sb2 = (uint32_t*)p; p += SBW * 4;
    float* dinv   = (float*)p;    p += NNODES * 4;
    int* glist    = (int*)p;      p += NLIST * 4;

    uint32_t ka0, kb0, ka1, kb1;
    tf2x32(0u, 42u, 0u, 0u, ka0, kb0);
    tf2x32(0u, 42u, 0u, 1u, ka1, kb1);

    hipMemsetAsync(d_ws, 0, zlen, stream);
    k_fused<<<dim3(NBLK), dim3(NTHR), 0, stream>>>(
        rows4, cols4, seeds, nSeeds, sb1, sb2, cand, hist0, hist1, scal,
        glist, dinv, planes, enc4p, msk4p, bar, E4, ka0, kb0, ka1, kb1);
}